// Round 13
// baseline (11968.134 us; speedup 1.0000x reference)
//
#include <hip/hip_runtime.h>
#include <stdint.h>

typedef __attribute__((ext_vector_type(8))) __bf16 bf16x8;
typedef __attribute__((ext_vector_type(4))) float f32x4;

#define BM 256
#define BN 256
#define BKT 32   // K elems per tile (one 32-KB {A,B} pair per buffer)

__device__ __forceinline__ unsigned short f2bf_rne(float f) {
  unsigned int u = __builtin_bit_cast(unsigned int, f);
  u += 0x7FFFu + ((u >> 16) & 1u);
  return (unsigned short)(u >> 16);
}

__global__ void cvt_f32_to_bf16(const float* __restrict__ in,
                                unsigned short* __restrict__ out, long n4) {
  long stride = (long)gridDim.x * blockDim.x;
  for (long i = (long)blockIdx.x * blockDim.x + threadIdx.x; i < n4; i += stride) {
    float4 v = reinterpret_cast<const float4*>(in)[i];
    ushort4 o;
    o.x = f2bf_rne(v.x); o.y = f2bf_rne(v.y);
    o.z = f2bf_rne(v.z); o.w = f2bf_rne(v.w);
    reinterpret_cast<ushort4*>(out)[i] = o;
  }
}

__global__ void cvt_i32_to_bf16(const int* __restrict__ in,
                                unsigned short* __restrict__ out, long n4) {
  long stride = (long)gridDim.x * blockDim.x;
  for (long i = (long)blockIdx.x * blockDim.x + threadIdx.x; i < n4; i += stride) {
    int4 v = reinterpret_cast<const int4*>(in)[i];
    ushort4 o;
    o.x = f2bf_rne((float)v.x); o.y = f2bf_rne((float)v.y);
    o.z = f2bf_rne((float)v.z); o.w = f2bf_rne((float)v.w);
    reinterpret_cast<ushort4*>(out)[i] = o;
  }
}

#define GLDS16(g, l)                                                          \
  __builtin_amdgcn_global_load_lds(                                           \
      (const __attribute__((address_space(1))) unsigned int*)(g),             \
      (__attribute__((address_space(3))) unsigned int*)(l), 16, 0, 0)

// Inline-asm ds_read_b128 (opaque to SIInsertWaitcnts; no clobbers in-loop
// so no hidden vmcnt(0) drains). rule #18: manual waits + sched_barrier(0).
typedef __attribute__((address_space(3))) const unsigned short lds_cu16;

template <int OFF>
__device__ __forceinline__ bf16x8 ldsb128(lds_cu16* p) {
  bf16x8 r;
  asm volatile("ds_read_b128 %0, %1 offset:%2" : "=v"(r) : "v"(p), "i"(OFF));
  return r;
}

#define BAR __builtin_amdgcn_s_barrier()
#define SCHEDB __builtin_amdgcn_sched_barrier(0)
#define LGKM_0 asm volatile("s_waitcnt lgkmcnt(0)")
#define LGKM_4 asm volatile("s_waitcnt lgkmcnt(4)")
#define VMC_0 asm volatile("s_waitcnt vmcnt(0)")

// 8 MFMAs on a 4x2 accumulator quadrant (all indices compile-time)
#define MFMA8(A4, B2, I0, J0)                                                 \
  _Pragma("unroll") for (int i = 0; i < 4; ++i)                               \
    _Pragma("unroll") for (int j = 0; j < 2; ++j)                             \
      acc[(I0) + i][(J0) + j] = __builtin_amdgcn_mfma_f32_16x16x32_bf16(      \
          A4[i], B2[j], acc[(I0) + i][(J0) + j], 0, 0, 0)

// 256x256 GEMM, T2-swizzled, DOUBLE-buffered (64 KiB LDS) so TWO blocks
// co-reside per CU (16 waves, 4/SIMD). R5-R12 proved intra-block scheduling
// cannot overlap the LDS and MFMA pipes: all 8 waves are barrier-locked in
// the same phase (MfmaUtil pinned 43-47% across 7 schedule variants at
// 2 waves/SIMD). The fix is TLP, not scheduling - a co-resident block in
// the complementary phase feeds the idle pipe (m114: co-scheduled waves
// overlap fully; m97's 912 TF = 3 blocks/CU of exactly this). vmcnt(0) at
// tile top is one-tile-old (cheap) and the other block hides the residue.
__global__ __launch_bounds__(512, 4) void gemm256_occ(
    const unsigned short* __restrict__ A,   // [M][K] bf16
    const unsigned short* __restrict__ W,   // [N][K] bf16
    const float* __restrict__ scale,        // [N]
    const float* __restrict__ bias,         // [N]
    float* __restrict__ C,                  // [M][N] f32
    int M, int N, int K) {
  __shared__ __align__(16) unsigned short As[2][256 * 32];  // 32 KiB
  __shared__ __align__(16) unsigned short Bs[2][256 * 32];  // 32 KiB

  const int tid = threadIdx.x;
  const int lane = tid & 63;
  const int wv = tid >> 6;       // 0..7
  const int wm = wv >> 2;        // 0..1  (wave row: 128 rows)
  const int wn = wv & 3;         // 0..3  (wave col: 64 cols)

  const int nwg = gridDim.x;
  const int bid = blockIdx.x;
  const int wg = ((nwg & 7) == 0) ? ((bid & 7) * (nwg >> 3) + (bid >> 3)) : bid;
  const int mT = M / BM;
  const int bm = wg % mT;        // M-fast: neighbors share W panel
  const int bn = wg / mT;

  const long aRow0 = (long)bm * BM;
  const long wRow0 = (long)bn * BN;

  // staging: chunk c = 16 rows x 64B; lane l -> linear dest slot, inverse-
  // swizzled source column (logical slot (l&3)^((l>>3)&3)).
  const int c0 = wv, c1 = 8 + wv;
  const int sr0 = 16 * c0 + (lane >> 2);
  const int sr1 = 16 * c1 + (lane >> 2);
  const int sc = (((lane & 3) ^ ((lane >> 3) & 3))) * 8;
  const unsigned short* aS0 = A + (aRow0 + sr0) * (long)K + sc;
  const unsigned short* aS1 = A + (aRow0 + sr1) * (long)K + sc;
  const unsigned short* wS0 = W + (wRow0 + sr0) * (long)K + sc;
  const unsigned short* wS1 = W + (wRow0 + sr1) * (long)K + sc;
  const int d0 = c0 * 512 + lane * 8;
  const int d1 = c1 * 512 + lane * 8;

  // ds_read bases: row*32 + swizzled-slot*8 (XOR term lane-constant)
  const int sx = (lane >> 4) ^ ((lane >> 1) & 3);
  const int rdA = (wm * 128 + (lane & 15)) * 32 + sx * 8;
  const int rdB = (wn * 64 + (lane & 15)) * 32 + sx * 8;

  f32x4 acc[8][4] = {};
  bf16x8 b0[2], b1[2], a0[4], a1[4];

  const int nk = K / BKT;   // 128 (guarded % 2 == 0)

  // prologue: stage tile 0 -> buf0
  GLDS16(aS0, &As[0][d0]);
  GLDS16(aS1, &As[0][d1]);
  GLDS16(wS0, &Bs[0][d0]);
  GLDS16(wS1, &Bs[0][d1]);

#define TILE_BODY(CUR, NXT, KOFF)                                             \
  {                                                                           \
    SCHEDB;                                                                   \
    VMC_0; /* tile CUR's DMA retired (issued one full tile ago) */            \
    BAR;   /* publish CUR; buf NXT's readers finished last tile */            \
    GLDS16(aS0 + (KOFF), &As[NXT][d0]);                                       \
    GLDS16(aS1 + (KOFF), &As[NXT][d1]);                                       \
    GLDS16(wS0 + (KOFF), &Bs[NXT][d0]);                                       \
    GLDS16(wS1 + (KOFF), &Bs[NXT][d1]);                                       \
    SCHEDB;                                                                   \
    {                                                                         \
      lds_cu16* pB = (lds_cu16*)&Bs[CUR][rdB];                                \
      lds_cu16* pA = (lds_cu16*)&As[CUR][rdA];                                \
      /* burst 1: 6 reads (B cols 0-31, A rows 0-63) */                       \
      b0[0] = ldsb128<0>(pB);    b0[1] = ldsb128<1024>(pB);                   \
      a0[0] = ldsb128<0>(pA);    a0[1] = ldsb128<1024>(pA);                   \
      a0[2] = ldsb128<2048>(pA); a0[3] = ldsb128<3072>(pA);                   \
      LGKM_0; SCHEDB;                                                         \
      /* burst 2: 2 reads (B cols 32-63), drains under q00 */                 \
      b1[0] = ldsb128<2048>(pB); b1[1] = ldsb128<3072>(pB);                   \
      SCHEDB;                                                                 \
      __builtin_amdgcn_s_setprio(1);                                          \
      MFMA8(a0, b0, 0, 0);                                                    \
      __builtin_amdgcn_s_setprio(0);                                          \
      SCHEDB;                                                                 \
      /* burst 3: 4 reads (A rows 64-127), drains under q01 */                \
      a1[0] = ldsb128<4096>(pA); a1[1] = ldsb128<5120>(pA);                   \
      a1[2] = ldsb128<6144>(pA); a1[3] = ldsb128<7168>(pA);                   \
      SCHEDB; LGKM_4; SCHEDB; /* b1 ready (a1's 4 still in flight) */         \
      __builtin_amdgcn_s_setprio(1);                                          \
      MFMA8(a0, b1, 0, 2);                                                    \
      __builtin_amdgcn_s_setprio(0);                                          \
      SCHEDB; LGKM_0; SCHEDB; /* a1 ready (drained under q01) */              \
      __builtin_amdgcn_s_setprio(1);                                          \
      MFMA8(a1, b0, 4, 0);                                                    \
      MFMA8(a1, b1, 4, 2);                                                    \
      __builtin_amdgcn_s_setprio(0);                                          \
    }                                                                         \
    SCHEDB;                                                                   \
  }

  for (int kt = 0; kt < nk; kt += 2) {
    const long ko1 = (long)(kt + 1) * BKT;                       // < nk
    const long ko2 = (kt + 2 < nk) ? (long)(kt + 2) * BKT : 0;   // wrap ok
    TILE_BODY(0, 1, ko1);
    TILE_BODY(1, 0, ko2);
  }
#undef TILE_BODY

  // epilogue: C/D frag layout col=lane&15, row=(lane>>4)*4+v
  const long col0 = wRow0 + wn * 64 + (lane & 15);
  float scl[4], bs[4];
#pragma unroll
  for (int j = 0; j < 4; ++j) {
    scl[j] = scale[col0 + j * 16];
    bs[j] = bias[col0 + j * 16];
  }
  const long row0 = aRow0 + wm * 128 + ((lane >> 4) << 2);
#pragma unroll
  for (int i = 0; i < 8; ++i) {
#pragma unroll
    for (int v = 0; v < 4; ++v) {
      float* cp = C + (row0 + i * 16 + v) * (long)N + col0;
#pragma unroll
      for (int j = 0; j < 4; ++j)
        cp[j * 16] = acc[i][j][v] * scl[j] + bs[j];
    }
  }
}

// correctness-only fallback
__global__ void naive_w8a16(const float* __restrict__ inp,
                            const int* __restrict__ qw,
                            const float* __restrict__ scale,
                            const float* __restrict__ bias,
                            float* __restrict__ out, long M, long N, long K) {
  long idx = (long)blockIdx.x * blockDim.x + threadIdx.x;
  if (idx >= M * N) return;
  long col = idx % N, row = idx / N;
  const float* a = inp + row * K;
  const int* w = qw + col * K;
  float s = 0.f;
  for (long k = 0; k < K; k += 4) {
    float4 av = *reinterpret_cast<const float4*>(&a[k]);
    int4 wv = *reinterpret_cast<const int4*>(&w[k]);
    s += av.x * (float)wv.x + av.y * (float)wv.y + av.z * (float)wv.z +
         av.w * (float)wv.w;
  }
  out[idx] = s * scale[col] + bias[col];
}

extern "C" void kernel_launch(void* const* d_in, const int* in_sizes, int n_in,
                              void* d_out, int out_size, void* d_ws,
                              size_t ws_size, hipStream_t stream) {
  const float* inp = (const float*)d_in[0];   // [B,S,D_IN] f32
  const int* qw = (const int*)d_in[1];        // [D_OUT,D_IN] i32
  const float* scale = (const float*)d_in[2]; // [D_OUT]
  const float* bias = (const float*)d_in[3];  // [D_OUT]
  float* out = (float*)d_out;                 // [B,S,D_OUT] f32

  const long N = in_sizes[2];                 // 16384
  const long K = (long)in_sizes[1] / N;       // 4096
  const long M = (long)in_sizes[0] / K;       // 8192

  const size_t aBytes = (size_t)M * K * 2;
  const size_t wBytes = (size_t)N * K * 2;
  const long nk = K / BKT;

  if (ws_size >= aBytes + wBytes && (M % BM) == 0 && (N % BN) == 0 &&
      (K % BKT) == 0 && nk >= 4 && (nk % 2) == 0) {
    unsigned short* Abf = (unsigned short*)d_ws;
    unsigned short* Wbf = (unsigned short*)((char*)d_ws + aBytes);
    cvt_f32_to_bf16<<<2048, 256, 0, stream>>>(inp, Abf, M * K / 4);
    cvt_i32_to_bf16<<<2048, 256, 0, stream>>>(qw, Wbf, N * K / 4);
    const int nwg = (int)((M / BM) * (N / BN));  // 2048
    gemm256_occ<<<nwg, 512, 0, stream>>>(Abf, Wbf, scale, bias, out, (int)M,
                                         (int)N, (int)K);
  } else {
    long total = M * N;
    naive_w8a16<<<(int)((total + 255) / 256), 256, 0, stream>>>(
        inp, qw, scale, bias, out, M, N, K);
  }
}

// Round 14
// 778.901 us; speedup vs baseline: 15.3654x; 15.3654x over previous
//
#include <hip/hip_runtime.h>
#include <stdint.h>

typedef __attribute__((ext_vector_type(4))) int iv4;      // 4 VGPRs (16B)
typedef __attribute__((ext_vector_type(4))) float f32x4;
typedef __attribute__((ext_vector_type(16))) char i8x16;

#define BM 256
#define BN 256
#define BKT 64   // K elems (bytes) per tile; one 16-KB A + 16-KB B per buffer

// ---- activation quantization: one block per row, per-row scale ----
__global__ __launch_bounds__(256) void quant_act(const float* __restrict__ in,
                                                 signed char* __restrict__ out,
                                                 float* __restrict__ s_a,
                                                 int K) {
  const int row = blockIdx.x;
  const int t = threadIdx.x;
  const float* a = in + (long)row * K;
  float4 v[4];
#pragma unroll
  for (int i = 0; i < 4; ++i)
    v[i] = reinterpret_cast<const float4*>(a)[t * 4 + i];
  float m = 0.f;
#pragma unroll
  for (int i = 0; i < 4; ++i) {
    m = fmaxf(m, fmaxf(fmaxf(fabsf(v[i].x), fabsf(v[i].y)),
                       fmaxf(fabsf(v[i].z), fabsf(v[i].w))));
  }
#pragma unroll
  for (int off = 32; off; off >>= 1) m = fmaxf(m, __shfl_xor(m, off));
  __shared__ float wmax[4];
  const int lane = t & 63, wvq = t >> 6;
  if (lane == 0) wmax[wvq] = m;
  __syncthreads();
  m = fmaxf(fmaxf(wmax[0], wmax[1]), fmaxf(wmax[2], wmax[3]));
  const float inv = m > 0.f ? 127.f / m : 0.f;
  if (t == 0) s_a[row] = m > 0.f ? m / 127.f : 0.f;
  i8x16 q;
#pragma unroll
  for (int i = 0; i < 4; ++i) {
    q[i * 4 + 0] = (char)(int)rintf(fminf(fmaxf(v[i].x * inv, -127.f), 127.f));
    q[i * 4 + 1] = (char)(int)rintf(fminf(fmaxf(v[i].y * inv, -127.f), 127.f));
    q[i * 4 + 2] = (char)(int)rintf(fminf(fmaxf(v[i].z * inv, -127.f), 127.f));
    q[i * 4 + 3] = (char)(int)rintf(fminf(fmaxf(v[i].w * inv, -127.f), 127.f));
  }
  reinterpret_cast<i8x16*>(out + (long)row * K)[t] = q;
}

// ---- weight pack: int32 (|v|<=127) -> int8, 16 elems/thread/iter ----
__global__ void pack_w(const int* __restrict__ in, signed char* __restrict__ out,
                       long n16) {
  long stride = (long)gridDim.x * blockDim.x;
  for (long i = (long)blockIdx.x * blockDim.x + threadIdx.x; i < n16; i += stride) {
    i8x16 q;
#pragma unroll
    for (int c = 0; c < 4; ++c) {
      int4 w = reinterpret_cast<const int4*>(in)[i * 4 + c];
      q[c * 4 + 0] = (char)w.x;
      q[c * 4 + 1] = (char)w.y;
      q[c * 4 + 2] = (char)w.z;
      q[c * 4 + 3] = (char)w.w;
    }
    reinterpret_cast<i8x16*>(out)[i] = q;
  }
}

#define GLDS16(g, l)                                                          \
  __builtin_amdgcn_global_load_lds(                                           \
      (const __attribute__((address_space(1))) unsigned int*)(g),             \
      (__attribute__((address_space(3))) unsigned int*)(l), 16, 0, 0)

// Inline-asm ds_read_b128 (opaque to SIInsertWaitcnts; no clobbers in-loop
// so no hidden vmcnt(0) drains). rule #18: manual waits + sched_barrier(0).
typedef __attribute__((address_space(3))) const signed char lds_c8;

template <int OFF>
__device__ __forceinline__ iv4 ldsb128(lds_c8* p) {
  iv4 r;
  asm volatile("ds_read_b128 %0, %1 offset:%2" : "=v"(r) : "v"(p), "i"(OFF));
  return r;
}

#define BAR __builtin_amdgcn_s_barrier()
#define SCHEDB __builtin_amdgcn_sched_barrier(0)
#define LGKM_0 asm volatile("s_waitcnt lgkmcnt(0)")
#define VMC_4 asm volatile("s_waitcnt vmcnt(4)")

// 16 i8 MFMAs: acc[I0..I0+3][0..3] += a[i] x b[j], K=64 consumed per MFMA
#define MFMA16I(A4, B4, I0)                                                   \
  _Pragma("unroll") for (int i = 0; i < 4; ++i)                               \
    _Pragma("unroll") for (int j = 0; j < 4; ++j)                             \
      acc[(I0) + i][j] = __builtin_amdgcn_mfma_i32_16x16x64_i8(               \
          A4[i], B4[j], acc[(I0) + i][j], 0, 0, 0)

// 256x256 int8 GEMM, R9/R12 skeleton unchanged (quad-buffer, never-drain
// vmcnt(4) DMA stream, T2 swizzle - LDS rows are 64B exactly as before, so
// staging/swizzle/ds_read constants are identical, just byte-typed).
// Per K-64 tile: 12 ds_read_b128 + 32 MFMA (vs bf16: 2x that per K-64).
// Epilogue: out = f32(acc_i32) * s_a[row] * s_w[col] + bias[col].
__global__ __launch_bounds__(512, 2) void gemm256_i8(
    const signed char* __restrict__ A,   // [M][K] i8 (row-quantized)
    const signed char* __restrict__ W,   // [N][K] i8
    const float* __restrict__ s_a,       // [M] activation row scales
    const float* __restrict__ scale,     // [N] weight col scales
    const float* __restrict__ bias,      // [N]
    float* __restrict__ C,               // [M][N] f32
    int M, int N, int K) {
  __shared__ __align__(16) signed char As[4][256 * 64];  // 64 KiB
  __shared__ __align__(16) signed char Bs[4][256 * 64];  // 64 KiB

  const int tid = threadIdx.x;
  const int lane = tid & 63;
  const int wv = tid >> 6;       // 0..7
  const int wm = wv >> 2;        // 0..1  (wave row: 128 rows)
  const int wn = wv & 3;         // 0..3  (wave col: 64 cols)

  const int nwg = gridDim.x;
  const int bid = blockIdx.x;
  const int wg = ((nwg & 7) == 0) ? ((bid & 7) * (nwg >> 3) + (bid >> 3)) : bid;
  const int mT = M / BM;
  const int bm = wg % mT;        // M-fast: neighbors share W panel
  const int bn = wg / mT;

  const long aRow0 = (long)bm * BM;
  const long wRow0 = (long)bn * BN;

  // staging: chunk c = 16 rows x 64B; lane l -> linear dest slot, inverse-
  // swizzled source column in BYTES (logical 16B-slot (l&3)^((l>>3)&3)).
  const int c0 = wv, c1 = 8 + wv;
  const int sr0 = 16 * c0 + (lane >> 2);
  const int sr1 = 16 * c1 + (lane >> 2);
  const int scB = (((lane & 3) ^ ((lane >> 3) & 3))) * 16;
  const signed char* aS0 = A + (aRow0 + sr0) * (long)K + scB;
  const signed char* aS1 = A + (aRow0 + sr1) * (long)K + scB;
  const signed char* wS0 = W + (wRow0 + sr0) * (long)K + scB;
  const signed char* wS1 = W + (wRow0 + sr1) * (long)K + scB;
  const int d0 = c0 * 1024 + lane * 16;   // byte offset in a buffer
  const int d1 = c1 * 1024 + lane * 16;

  // ds_read bases (bytes): row*64 + swizzled 16B-slot*16; i8 frag: lane l ->
  // row (l&15), k-bytes (l>>4)*16..+15 (K=64 per MFMA). XOR term lane-const.
  const int sx = (lane >> 4) ^ ((lane >> 1) & 3);
  const int rdA = (wm * 128 + (lane & 15)) * 64 + sx * 16;
  const int rdB = (wn * 64 + (lane & 15)) * 64 + sx * 16;

  iv4 acc[8][4] = {};
  iv4 b[4], a0[4], a1[4];

  const int nk = K / BKT;   // 64 (guarded % 4 == 0)

  // prologue: stage tile 0 -> buf0, tile 1 -> buf1 (8 loads in flight)
  GLDS16(aS0, &As[0][d0]);
  GLDS16(aS1, &As[0][d1]);
  GLDS16(wS0, &Bs[0][d0]);
  GLDS16(wS1, &Bs[0][d1]);
  GLDS16(aS0 + BKT, &As[1][d0]);
  GLDS16(aS1 + BKT, &As[1][d1]);
  GLDS16(wS0 + BKT, &Bs[1][d0]);
  GLDS16(wS1 + BKT, &Bs[1][d1]);

#define TILE_BODY(CUR, STG, KOFF)                                             \
  {                                                                           \
    SCHEDB;                                                                   \
    VMC_4; /* tile CUR's 4 oldest retired; next tile's 4 stay in flight */    \
    BAR;   /* publish CUR's DMA writes; buf STG's readers long done */        \
    GLDS16(aS0 + (KOFF), &As[STG][d0]);                                       \
    GLDS16(aS1 + (KOFF), &As[STG][d1]);                                       \
    GLDS16(wS0 + (KOFF), &Bs[STG][d0]);                                       \
    GLDS16(wS1 + (KOFF), &Bs[STG][d1]);                                       \
    SCHEDB;                                                                   \
    {                                                                         \
      lds_c8* pB = (lds_c8*)&Bs[CUR][rdB];                                    \
      lds_c8* pA = (lds_c8*)&As[CUR][rdA];                                    \
      b[0] = ldsb128<0>(pB);    b[1] = ldsb128<1024>(pB);                     \
      b[2] = ldsb128<2048>(pB); b[3] = ldsb128<3072>(pB);                     \
      a0[0] = ldsb128<0>(pA);    a0[1] = ldsb128<1024>(pA);                   \
      a0[2] = ldsb128<2048>(pA); a0[3] = ldsb128<3072>(pA);                   \
      LGKM_0; SCHEDB;                                                         \
      __builtin_amdgcn_s_setprio(1);                                          \
      a1[0] = ldsb128<4096>(pA); a1[1] = ldsb128<5120>(pA);                   \
      a1[2] = ldsb128<6144>(pA); a1[3] = ldsb128<7168>(pA);                   \
      SCHEDB;                                                                 \
      MFMA16I(a0, b, 0);   /* a1's reads drain under these 16 MFMAs */        \
      __builtin_amdgcn_s_setprio(0);                                          \
      SCHEDB; LGKM_0; SCHEDB;                                                 \
      __builtin_amdgcn_s_setprio(1);                                          \
      MFMA16I(a1, b, 4);                                                      \
      __builtin_amdgcn_s_setprio(0);                                          \
    }                                                                         \
    SCHEDB;                                                                   \
  }

  for (int kt = 0; kt < nk; kt += 4) {
    const long ko2 = (long)(kt + 2) * BKT;                        // < nk
    const long ko3 = (long)(kt + 3) * BKT;                        // < nk
    const long ko4 = (kt + 4 < nk) ? (long)(kt + 4) * BKT : 0;    // wrap ok
    const long ko5 = (kt + 5 < nk) ? (long)(kt + 5) * BKT : 0;    // wrap ok
    TILE_BODY(0, 2, ko2);
    TILE_BODY(1, 3, ko3);
    TILE_BODY(2, 0, ko4);
    TILE_BODY(3, 1, ko5);
  }
#undef TILE_BODY

  // epilogue: C/D frag layout col=lane&15, row=(lane>>4)*4+v (dtype-indep)
  const long col0 = wRow0 + wn * 64 + (lane & 15);
  float scl[4], bs[4];
#pragma unroll
  for (int j = 0; j < 4; ++j) {
    scl[j] = scale[col0 + j * 16];
    bs[j] = bias[col0 + j * 16];
  }
  const long row0 = aRow0 + wm * 128 + ((lane >> 4) << 2);
#pragma unroll
  for (int i = 0; i < 8; ++i) {
#pragma unroll
    for (int v = 0; v < 4; ++v) {
      const float rs = s_a[row0 + i * 16 + v];
      float* cp = C + (row0 + i * 16 + v) * (long)N + col0;
#pragma unroll
      for (int j = 0; j < 4; ++j)
        cp[j * 16] = (float)acc[i][j][v] * (rs * scl[j]) + bs[j];
    }
  }
}

// correctness-only fallback (reads original fp32/int32 inputs)
__global__ void naive_w8a16(const float* __restrict__ inp,
                            const int* __restrict__ qw,
                            const float* __restrict__ scale,
                            const float* __restrict__ bias,
                            float* __restrict__ out, long M, long N, long K) {
  long idx = (long)blockIdx.x * blockDim.x + threadIdx.x;
  if (idx >= M * N) return;
  long col = idx % N, row = idx / N;
  const float* a = inp + row * K;
  const int* w = qw + col * K;
  float s = 0.f;
  for (long k = 0; k < K; k += 4) {
    float4 av = *reinterpret_cast<const float4*>(&a[k]);
    int4 wv = *reinterpret_cast<const int4*>(&w[k]);
    s += av.x * (float)wv.x + av.y * (float)wv.y + av.z * (float)wv.z +
         av.w * (float)wv.w;
  }
  out[idx] = s * scale[col] + bias[col];
}

extern "C" void kernel_launch(void* const* d_in, const int* in_sizes, int n_in,
                              void* d_out, int out_size, void* d_ws,
                              size_t ws_size, hipStream_t stream) {
  const float* inp = (const float*)d_in[0];   // [B,S,D_IN] f32
  const int* qw = (const int*)d_in[1];        // [D_OUT,D_IN] i32
  const float* scale = (const float*)d_in[2]; // [D_OUT]
  const float* bias = (const float*)d_in[3];  // [D_OUT]
  float* out = (float*)d_out;                 // [B,S,D_OUT] f32

  const long N = in_sizes[2];                 // 16384
  const long K = (long)in_sizes[1] / N;       // 4096
  const long M = (long)in_sizes[0] / K;       // 8192

  const size_t aB = (size_t)M * K;            // 32 MiB (i8)
  const size_t wB = (size_t)N * K;            // 64 MiB (i8)
  const size_t sB = (size_t)M * 4;            // row scales
  const long nk = K / BKT;

  if (ws_size >= aB + wB + sB && (M % BM) == 0 && (N % BN) == 0 &&
      K == 4096 && nk >= 8 && (nk % 4) == 0) {
    signed char* Ai8 = (signed char*)d_ws;
    signed char* Wi8 = (signed char*)d_ws + aB;
    float* sA = (float*)((char*)d_ws + aB + wB);
    quant_act<<<(int)M, 256, 0, stream>>>(inp, Ai8, sA, (int)K);
    pack_w<<<2048, 256, 0, stream>>>(qw, Wi8, N * K / 16);
    const int nwg = (int)((M / BM) * (N / BN));  // 2048
    gemm256_i8<<<nwg, 512, 0, stream>>>(Ai8, Wi8, sA, scale, bias, out,
                                        (int)M, (int)N, (int)K);
  } else {
    long total = M * N;
    naive_w8a16<<<(int)((total + 255) / 256), 256, 0, stream>>>(
        inp, qw, scale, bias, out, M, N, K);
  }
}